// Round 2
// baseline (349.857 us; speedup 1.0000x reference)
//
#include <hip/hip_runtime.h>

// PerformerSelfAttention B=2 L=2048 D=1024 H=16 hd=64 fp32.
// Linear-attention identity: ctx = qf @ (Kf^T V) / (sum_d qf + eps).
// GEMMs via bf16 hi/lo split MFMA (3 products, fp32-equivalent accuracy).
// k-slot permutation trick: A and B fragments loaded with the SAME assumed
// slot->k map, so the unknown HW map cancels. C/D layout is the HW-verified
// col=lane&15, row=(lane>>4)*4+reg (learn_hip m89/m91).

#define EPSV 1e-6f
#define MDIM 4096
#define DDIM 1024
#define HEADS 16
#define HD 64

typedef __attribute__((ext_vector_type(8))) short short8;   // bf16x8 frag (4 VGPR)
typedef __attribute__((ext_vector_type(4))) float f32x4;    // acc frag

__device__ inline ushort f2bf(float x) {
    unsigned int b = __float_as_uint(x);
    unsigned int r = (b + 0x7FFFu + ((b >> 16) & 1u)) >> 16;   // RNE
    return (ushort)r;
}
__device__ inline float bf2f(ushort u) { return __uint_as_float(((unsigned int)u) << 16); }

__device__ inline void gld_lds16(const ushort* g, ushort* l) {
    __builtin_amdgcn_global_load_lds(
        (const __attribute__((address_space(1))) unsigned int*)g,
        (__attribute__((address_space(3))) unsigned int*)l, 16, 0, 0);
}

// ---------------- fp32 -> bf16 hi/lo split (X and ctx path uses in-kernel emit) ----------------
__global__ __launch_bounds__(256) void split_kernel(const float* __restrict__ x,
                                                    ushort* __restrict__ hi,
                                                    ushort* __restrict__ lo)
{
    const int i = (blockIdx.x * 256 + threadIdx.x) * 4;
    const float4 v = *(const float4*)&x[i];
    ushort4 h, l;
    h.x = f2bf(v.x); l.x = f2bf(v.x - bf2f(h.x));
    h.y = f2bf(v.y); l.y = f2bf(v.y - bf2f(h.y));
    h.z = f2bf(v.z); l.z = f2bf(v.z - bf2f(h.z));
    h.w = f2bf(v.w); l.w = f2bf(v.w - bf2f(h.w));
    *(ushort4*)&hi[i] = h;
    *(ushort4*)&lo[i] = l;
}

// ---------------- weight split + transpose: W[k][n] fp32 -> WT{hi,lo}[n][k] bf16 ----------------
__global__ __launch_bounds__(256) void wsplit_kernel(
    const float* __restrict__ W0, const float* __restrict__ W1,
    const float* __restrict__ W2, const float* __restrict__ W3,
    ushort* __restrict__ T0h, ushort* __restrict__ T0l,
    ushort* __restrict__ T1h, ushort* __restrict__ T1l,
    ushort* __restrict__ T2h, ushort* __restrict__ T2l,
    ushort* __restrict__ T3h, ushort* __restrict__ T3l)
{
    const float* W; ushort* Th; ushort* Tl;
    if (blockIdx.z == 0)      { W = W0; Th = T0h; Tl = T0l; }
    else if (blockIdx.z == 1) { W = W1; Th = T1h; Tl = T1l; }
    else if (blockIdx.z == 2) { W = W2; Th = T2h; Tl = T2l; }
    else                      { W = W3; Th = T3h; Tl = T3l; }

    __shared__ float t[32][33];
    const int tt = threadIdx.x;
    const int r = tt >> 3, c4 = (tt & 7) * 4;
    const int k0 = blockIdx.x * 32, n0 = blockIdx.y * 32;

    const float4 v = *(const float4*)&W[(size_t)(k0 + r) * DDIM + n0 + c4];
    t[r][c4 + 0] = v.x; t[r][c4 + 1] = v.y; t[r][c4 + 2] = v.z; t[r][c4 + 3] = v.w;
    __syncthreads();

    const float x0 = t[c4 + 0][r], x1 = t[c4 + 1][r], x2 = t[c4 + 2][r], x3 = t[c4 + 3][r];
    ushort4 h, l;
    h.x = f2bf(x0); l.x = f2bf(x0 - bf2f(h.x));
    h.y = f2bf(x1); l.y = f2bf(x1 - bf2f(h.y));
    h.z = f2bf(x2); l.z = f2bf(x2 - bf2f(h.z));
    h.w = f2bf(x3); l.w = f2bf(x3 - bf2f(h.w));
    *(ushort4*)&Th[(size_t)(n0 + r) * DDIM + k0 + c4] = h;
    *(ushort4*)&Tl[(size_t)(n0 + r) * DDIM + k0 + c4] = l;
}

// ---------------- bf16x3 MFMA GEMM: C[M,1024] = A[M,1024] @ BT^T + bias ----------------
// 128x128 tile, BK=32, 4 waves (2x2), each wave 4x4 frags of 16x16x32.
// LDS fragment-major: region{Ahi,Alo,Bhi,Blo} x 8 frags x 1KB; ds_read_b128 linear.
__global__ __launch_bounds__(256, 2) void gemm_mfma(
    const ushort* __restrict__ Ahi, const ushort* __restrict__ Alo,
    const ushort* __restrict__ B0h, const ushort* __restrict__ B0l,
    const ushort* __restrict__ B1h, const ushort* __restrict__ B1l,
    const ushort* __restrict__ B2h, const ushort* __restrict__ B2l,
    const float* __restrict__ bias0, const float* __restrict__ bias1, const float* __restrict__ bias2,
    float* __restrict__ C0, float* __restrict__ C1, float* __restrict__ C2)
{
    const ushort* Bh; const ushort* Bl; const float* bias; float* C;
    if (blockIdx.z == 0)      { Bh = B0h; Bl = B0l; bias = bias0; C = C0; }
    else if (blockIdx.z == 1) { Bh = B1h; Bl = B1l; bias = bias1; C = C1; }
    else                      { Bh = B2h; Bl = B2l; bias = bias2; C = C2; }

    __shared__ __align__(16) ushort lds[4][8][512];   // 32 KB

    const int tid = threadIdx.x;
    const int w = tid >> 6, l = tid & 63;
    const int row0 = blockIdx.x * 128, col0 = blockIdx.y * 128;
    const int wr = w >> 1, wc = w & 1;

    // staging role: wave 0 Ahi, 1 Alo, 2 Bhi, 3 Blo. frag f = 16 outer rows.
    // lane element: outer = f*16 + (l&15), k = (l>>4)*8 (+j contiguous, 16B)
    const ushort* gs; int outer0;
    if (w == 0)      { gs = Ahi; outer0 = row0; }
    else if (w == 1) { gs = Alo; outer0 = row0; }
    else if (w == 2) { gs = Bh;  outer0 = col0; }
    else             { gs = Bl;  outer0 = col0; }
    const size_t lanebase = (size_t)(outer0 + (l & 15)) * DDIM + ((l >> 4) * 8);

    f32x4 acc[4][4];
    #pragma unroll
    for (int i = 0; i < 4; ++i)
        #pragma unroll
        for (int j = 0; j < 4; ++j) acc[i][j] = (f32x4){0.f, 0.f, 0.f, 0.f};

    for (int kc = 0; kc < DDIM; kc += 32) {
        __syncthreads();   // prior K-step's ds_reads done before overwrite
        #pragma unroll
        for (int f = 0; f < 8; ++f)
            gld_lds16(gs + lanebase + (size_t)f * 16 * DDIM + kc, &lds[w][f][0]);
        __syncthreads();   // vmcnt(0) drain: staged data visible

        short8 ah[4], al[4], bh[4], bl[4];
        #pragma unroll
        for (int i = 0; i < 4; ++i) {
            ah[i] = *(const short8*)&lds[0][wr * 4 + i][l * 8];
            al[i] = *(const short8*)&lds[1][wr * 4 + i][l * 8];
            bh[i] = *(const short8*)&lds[2][wc * 4 + i][l * 8];
            bl[i] = *(const short8*)&lds[3][wc * 4 + i][l * 8];
        }
        #pragma unroll
        for (int i = 0; i < 4; ++i)
            #pragma unroll
            for (int j = 0; j < 4; ++j) {
                acc[i][j] = __builtin_amdgcn_mfma_f32_16x16x32_bf16(ah[i], bh[j], acc[i][j], 0, 0, 0);
                acc[i][j] = __builtin_amdgcn_mfma_f32_16x16x32_bf16(ah[i], bl[j], acc[i][j], 0, 0, 0);
                acc[i][j] = __builtin_amdgcn_mfma_f32_16x16x32_bf16(al[i], bh[j], acc[i][j], 0, 0, 0);
            }
    }

    // epilogue: C/D map col=lane&15, row=(lane>>4)*4+q  (HW-verified)
    #pragma unroll
    for (int j = 0; j < 4; ++j) {
        const int col = col0 + (wc * 4 + j) * 16 + (l & 15);
        const float bb = bias[col];
        #pragma unroll
        for (int i = 0; i < 4; ++i) {
            const int rbase = row0 + (wr * 4 + i) * 16 + (l >> 4) * 4;
            #pragma unroll
            for (int q = 0; q < 4; ++q)
                C[(size_t)(rbase + q) * DDIM + col] = acc[i][j][q] + bb;
        }
    }
}

// ---------------- feature map: softmax-normalized positive features over hd=64 ----------------
__global__ __launch_bounds__(256) void feature_kernel(float* __restrict__ buf,
                                                      float* __restrict__ den)
{
    const int wid  = blockIdx.x * 4 + (threadIdx.x >> 6);
    const int lane = threadIdx.x & 63;
    const int row = wid >> 4;
    const int h   = wid & 15;
    float* p = buf + (size_t)row * DDIM + h * HD;

    const float v = p[lane];
    float m = v;
    #pragma unroll
    for (int o = 32; o; o >>= 1) m = fmaxf(m, __shfl_xor(m, o, 64));
    const float e = expf(v - m);
    float s = e;
    #pragma unroll
    for (int o = 32; o; o >>= 1) s += __shfl_xor(s, o, 64);
    const float q = e / (s + EPSV);
    p[lane] = q;
    if (den != nullptr) {
        float d = q;
        #pragma unroll
        for (int o = 32; o; o >>= 1) d += __shfl_xor(d, o, 64);
        if (lane == 0) den[wid] = d;
    }
}

// ---------------- KV = Kf^T V per head, 8-way m-split ----------------
#define MSUB 32
__global__ __launch_bounds__(256) void kv_partial_kernel(
    const float* __restrict__ Kf, const float* __restrict__ V, float* __restrict__ KVp)
{
    const int z = blockIdx.x;
    const int chunk = z & 7;
    const int bh = z >> 3;
    const int h = bh & 15;
    const int b = bh >> 4;

    __shared__ float Ks[MSUB][HD];
    __shared__ float Vs[MSUB][HD];

    const int t = threadIdx.x;
    const int d0 = (t >> 4) * 4;
    const int e0 = (t & 15) * 4;
    float acc[4][4];
    #pragma unroll
    for (int i = 0; i < 4; ++i)
        #pragma unroll
        for (int j = 0; j < 4; ++j) acc[i][j] = 0.f;

    const int base_tok = b * 2048 + chunk * 256;
    for (int sc = 0; sc < 8; ++sc) {
        __syncthreads();
        #pragma unroll
        for (int u = 0; u < 2; ++u) {
            const int f = t + u * 256;
            const int tok = f >> 4;
            const int c4 = (f & 15) * 4;
            const size_t g = (size_t)(base_tok + sc * MSUB + tok) * DDIM + h * HD + c4;
            *(float4*)&Ks[tok][c4] = *(const float4*)&Kf[g];
            *(float4*)&Vs[tok][c4] = *(const float4*)&V[g];
        }
        __syncthreads();
        #pragma unroll
        for (int mm = 0; mm < MSUB; ++mm) {
            const float4 k4 = *(const float4*)&Ks[mm][d0];
            const float4 v4 = *(const float4*)&Vs[mm][e0];
            const float kr[4] = {k4.x, k4.y, k4.z, k4.w};
            const float vr[4] = {v4.x, v4.y, v4.z, v4.w};
            #pragma unroll
            for (int i = 0; i < 4; ++i)
                #pragma unroll
                for (int j = 0; j < 4; ++j)
                    acc[i][j] = fmaf(kr[i], vr[j], acc[i][j]);
        }
    }
    float* outp = KVp + (size_t)z * 4096;
    #pragma unroll
    for (int i = 0; i < 4; ++i)
        *(float4*)&outp[(d0 + i) * HD + e0] =
            make_float4(acc[i][0], acc[i][1], acc[i][2], acc[i][3]);
}

__global__ __launch_bounds__(256) void kv_reduce_kernel(const float* __restrict__ KVp,
                                                        float* __restrict__ KV)
{
    const int idx = blockIdx.x * 256 + threadIdx.x;
    const int bh = idx >> 12;
    const int off = idx & 4095;
    float s = 0.f;
    #pragma unroll
    for (int c = 0; c < 8; ++c) s += KVp[(size_t)(bh * 8 + c) * 4096 + off];
    KV[idx] = s;
}

// ---------------- context = qf @ KV / (den+eps) -> bf16 hi/lo ----------------
__global__ __launch_bounds__(256) void context_kernel(
    const float* __restrict__ QF, const float* __restrict__ KV, const float* __restrict__ den,
    ushort* __restrict__ Chi, ushort* __restrict__ Clo)
{
    const int z = blockIdx.x;
    const int tc = z & 31;
    const int bh = z >> 5;
    const int h = bh & 15;
    const int b = bh >> 4;

    __shared__ float KVs[HD][HD];
    const int t = threadIdx.x;
    #pragma unroll
    for (int u = 0; u < 4; ++u) {
        const int f = t + u * 256;
        *(float4*)&KVs[0][f * 4] = *(const float4*)&KV[(size_t)bh * 4096 + f * 4];
    }
    __syncthreads();

    const int wave = t >> 6;
    const int lane = t & 63;
    for (int it = 0; it < 16; ++it) {
        const int tok = tc * 64 + it * 4 + wave;
        const int row = b * 2048 + tok;
        const size_t idx = (size_t)row * DDIM + h * HD + lane;
        const float qv = QF[idx];
        float acc = 0.f;
        #pragma unroll
        for (int e = 0; e < 64; ++e) {
            const float qe = __shfl(qv, e, 64);
            acc = fmaf(qe, KVs[e][lane], acc);
        }
        const float r = acc / (den[row * HEADS + h] + EPSV);
        const ushort hh = f2bf(r);
        Chi[idx] = hh;
        Clo[idx] = f2bf(r - bf2f(hh));
    }
}

// ---------------- launch ----------------
extern "C" void kernel_launch(void* const* d_in, const int* in_sizes, int n_in,
                              void* d_out, int out_size, void* d_ws, size_t ws_size,
                              hipStream_t stream)
{
    const float* X  = (const float*)d_in[0];
    const float* Wq = (const float*)d_in[1];
    const float* bq = (const float*)d_in[2];
    const float* Wk = (const float*)d_in[3];
    const float* bk = (const float*)d_in[4];
    const float* Wv = (const float*)d_in[5];
    const float* bv = (const float*)d_in[6];
    const float* Wo = (const float*)d_in[7];
    const float* bo = (const float*)d_in[8];
    float* out = (float*)d_out;

    // ws layout: Q|K|V fp32 (48MB) | den | KV | KVp | Xhi|Xlo (16MB, reused as ctx hi/lo)
    //            | 4x WT hi/lo bf16 (16MB)   total ~85MB
    float* ws  = (float*)d_ws;
    float* Q   = ws;
    float* Kb  = ws + 4194304;
    float* Vb  = ws + 8388608;
    float* den = ws + 12582912;
    float* KV  = den + 65536;
    float* KVp = KV + 131072;
    ushort* Xhi = (ushort*)(KVp + 1048576);
    ushort* Xlo = Xhi + 4194304;
    ushort* Wqh = Xlo + 4194304;
    ushort* Wql = Wqh + 1048576;
    ushort* Wkh = Wql + 1048576;
    ushort* Wkl = Wkh + 1048576;
    ushort* Wvh = Wkl + 1048576;
    ushort* Wvl = Wvh + 1048576;
    ushort* Woh = Wvl + 1048576;
    ushort* Wol = Woh + 1048576;
    ushort* Chi = Xhi;   // ctx aliases X (X dead after QKV GEMM)
    ushort* Clo = Xlo;

    // 1) fp32 -> bf16 hi/lo (X) and split+transpose (weights)
    split_kernel<<<4096, 256, 0, stream>>>(X, Xhi, Xlo);
    wsplit_kernel<<<dim3(32, 32, 4), 256, 0, stream>>>(
        Wq, Wk, Wv, Wo, Wqh, Wql, Wkh, Wkl, Wvh, Wvl, Woh, Wol);

    // 2) fused QKV projection (bf16x3 MFMA)
    gemm_mfma<<<dim3(32, 8, 3), 256, 0, stream>>>(
        Xhi, Xlo, Wqh, Wql, Wkh, Wkl, Wvh, Wvl, bq, bk, bv, Q, Kb, Vb);

    // 3) positive feature maps (q also stores den)
    feature_kernel<<<16384, 256, 0, stream>>>(Q, den);
    feature_kernel<<<16384, 256, 0, stream>>>(Kb, nullptr);

    // 4) KV = Kf^T V per head
    kv_partial_kernel<<<256, 256, 0, stream>>>(Kb, Vb, KVp);
    kv_reduce_kernel<<<512, 256, 0, stream>>>(KVp, KV);

    // 5) context -> bf16 hi/lo
    context_kernel<<<1024, 256, 0, stream>>>(Q, KV, den, Chi, Clo);

    // 6) output projection
    gemm_mfma<<<dim3(32, 8, 1), 256, 0, stream>>>(
        Chi, Clo, Woh, Wol, Woh, Wol, Woh, Wol, bo, bo, bo, out, out, out);
}

// Round 8
// 312.302 us; speedup vs baseline: 1.1203x; 1.1203x over previous
//
#include <hip/hip_runtime.h>

// PerformerSelfAttention B=2 L=2048 D=1024 H=16 hd=64 fp32.
// Linear-attention identity: ctx = qf @ (Kf^T V) / (sum_d qf + eps).
// GEMMs: fp16 MFMA, B-side hi/lo split (2 products):
//   C = A_f16 * Bh + (A_f16 * Bl_scaled) * 2^-8,  Bl_scaled = (B - Bh)*256
// (scaling keeps Bl out of fp16 subnormal range; error = A rounding only,
//  rel RMS ~2.8e-4). k-slot permutation trick: A and B fragments use the
// SAME assumed slot->k map so the HW map cancels. C/D layout: col=lane&15,
// row=(lane>>4)*4+reg (HW-verified, dtype-independent).
// [5th resubmission: rounds 3-7 timed out before running this experiment.]

#define EPSV 1e-6f
#define MDIM 4096
#define DDIM 1024
#define HEADS 16
#define HD 64

typedef __attribute__((ext_vector_type(8))) _Float16 half8;
typedef __attribute__((ext_vector_type(4))) _Float16 half4;
typedef __attribute__((ext_vector_type(4))) float f32x4;

__device__ inline void gld_lds16(const _Float16* g, _Float16* l) {
    __builtin_amdgcn_global_load_lds(
        (const __attribute__((address_space(1))) unsigned int*)g,
        (__attribute__((address_space(3))) unsigned int*)l, 16, 0, 0);
}

// ---------------- X fp32 -> fp16 ----------------
__global__ __launch_bounds__(256) void xhalf_kernel(const float* __restrict__ x,
                                                    _Float16* __restrict__ xh)
{
    const int i = (blockIdx.x * 256 + threadIdx.x) * 8;
    const float4 v0 = *(const float4*)&x[i];
    const float4 v1 = *(const float4*)&x[i + 4];
    half8 h;
    h[0] = (_Float16)v0.x; h[1] = (_Float16)v0.y; h[2] = (_Float16)v0.z; h[3] = (_Float16)v0.w;
    h[4] = (_Float16)v1.x; h[5] = (_Float16)v1.y; h[6] = (_Float16)v1.z; h[7] = (_Float16)v1.w;
    *(half8*)&xh[i] = h;
}

// ---------------- W[k][n] fp32 -> WT hi [n][k] fp16, WT lo-scaled [n][k] fp16 ----------------
__global__ __launch_bounds__(256) void wsplit_kernel(
    const float* __restrict__ W0, const float* __restrict__ W1,
    const float* __restrict__ W2, const float* __restrict__ W3,
    _Float16* __restrict__ T0h, _Float16* __restrict__ T0l,
    _Float16* __restrict__ T1h, _Float16* __restrict__ T1l,
    _Float16* __restrict__ T2h, _Float16* __restrict__ T2l,
    _Float16* __restrict__ T3h, _Float16* __restrict__ T3l)
{
    const float* W; _Float16* Th; _Float16* Tl;
    if (blockIdx.z == 0)      { W = W0; Th = T0h; Tl = T0l; }
    else if (blockIdx.z == 1) { W = W1; Th = T1h; Tl = T1l; }
    else if (blockIdx.z == 2) { W = W2; Th = T2h; Tl = T2l; }
    else                      { W = W3; Th = T3h; Tl = T3l; }

    __shared__ float t[32][33];
    const int tt = threadIdx.x;
    const int r = tt >> 3, c4 = (tt & 7) * 4;
    const int k0 = blockIdx.x * 32, n0 = blockIdx.y * 32;

    const float4 v = *(const float4*)&W[(size_t)(k0 + r) * DDIM + n0 + c4];
    t[r][c4 + 0] = v.x; t[r][c4 + 1] = v.y; t[r][c4 + 2] = v.z; t[r][c4 + 3] = v.w;
    __syncthreads();

    const float x0 = t[c4 + 0][r], x1 = t[c4 + 1][r], x2 = t[c4 + 2][r], x3 = t[c4 + 3][r];
    half4 h, l;
    h[0] = (_Float16)x0; l[0] = (_Float16)((x0 - (float)h[0]) * 256.0f);
    h[1] = (_Float16)x1; l[1] = (_Float16)((x1 - (float)h[1]) * 256.0f);
    h[2] = (_Float16)x2; l[2] = (_Float16)((x2 - (float)h[2]) * 256.0f);
    h[3] = (_Float16)x3; l[3] = (_Float16)((x3 - (float)h[3]) * 256.0f);
    *(half4*)&Th[(size_t)(n0 + r) * DDIM + k0 + c4] = h;
    *(half4*)&Tl[(size_t)(n0 + r) * DDIM + k0 + c4] = l;
}

// ---------------- fp16 2-product MFMA GEMM ----------------
// Block tile 128 x (32*WJ), BK=32, 4 waves (2x2), wave tile 64 x (16*WJ).
// LDS fragment-major: NF = 8 + 4*WJ frags x 1KB; all ds_read_b128 linear.
template<int WJ>
__global__ __launch_bounds__(256, 2) void gemm_mfma(
    const _Float16* __restrict__ A,
    const _Float16* __restrict__ B0h, const _Float16* __restrict__ B0l,
    const _Float16* __restrict__ B1h, const _Float16* __restrict__ B1l,
    const _Float16* __restrict__ B2h, const _Float16* __restrict__ B2l,
    const float* __restrict__ bias0, const float* __restrict__ bias1, const float* __restrict__ bias2,
    float* __restrict__ C0, float* __restrict__ C1, float* __restrict__ C2)
{
    const _Float16* Bh; const _Float16* Bl; const float* bias; float* C;
    if (blockIdx.z == 0)      { Bh = B0h; Bl = B0l; bias = bias0; C = C0; }
    else if (blockIdx.z == 1) { Bh = B1h; Bl = B1l; bias = bias1; C = C1; }
    else                      { Bh = B2h; Bl = B2l; bias = bias2; C = C2; }

    constexpr int FA = 8;           // A frags (128 rows)
    constexpr int FB = 2 * WJ;      // Bh frags (= Bl frags)
    constexpr int NF = FA + 2 * FB;
    constexpr int FPW = NF / 4;     // frags staged per wave

    __shared__ __align__(16) _Float16 lds[NF * 512];

    const int tid = threadIdx.x;
    const int w = tid >> 6, l = tid & 63;
    const int row0 = blockIdx.x * 128, col0 = blockIdx.y * (32 * WJ);
    const int wr = w >> 1, wc = w & 1;

    const int lrow = (l & 15);
    const int lk   = (l >> 4) * 8;

    f32x4 acc1[4][WJ], acc2[4][WJ];
    #pragma unroll
    for (int i = 0; i < 4; ++i)
        #pragma unroll
        for (int j = 0; j < WJ; ++j) {
            acc1[i][j] = (f32x4){0.f, 0.f, 0.f, 0.f};
            acc2[i][j] = (f32x4){0.f, 0.f, 0.f, 0.f};
        }

    for (int kc = 0; kc < DDIM; kc += 32) {
        __syncthreads();   // prior K-step's ds_reads done before overwrite
        #pragma unroll
        for (int u = 0; u < FPW; ++u) {
            const int g = w * FPW + u;       // wave-uniform
            const _Float16* src; int outer;
            if (g < FA)           { src = A;  outer = row0 + g * 16; }
            else if (g < FA + FB) { src = Bh; outer = col0 + (g - FA) * 16; }
            else                  { src = Bl; outer = col0 + (g - FA - FB) * 16; }
            gld_lds16(src + (size_t)(outer + lrow) * DDIM + kc + lk, &lds[g * 512]);
        }
        __syncthreads();   // vmcnt(0) drained before barrier by compiler

        half8 a[4], bh[WJ], bl[WJ];
        #pragma unroll
        for (int i = 0; i < 4; ++i)
            a[i] = *(const half8*)&lds[(wr * 4 + i) * 512 + l * 8];
        #pragma unroll
        for (int j = 0; j < WJ; ++j) {
            bh[j] = *(const half8*)&lds[(FA + wc * WJ + j) * 512 + l * 8];
            bl[j] = *(const half8*)&lds[(FA + FB + wc * WJ + j) * 512 + l * 8];
        }
        #pragma unroll
        for (int i = 0; i < 4; ++i)
            #pragma unroll
            for (int j = 0; j < WJ; ++j) {
                acc1[i][j] = __builtin_amdgcn_mfma_f32_16x16x32_f16(a[i], bh[j], acc1[i][j], 0, 0, 0);
                acc2[i][j] = __builtin_amdgcn_mfma_f32_16x16x32_f16(a[i], bl[j], acc2[i][j], 0, 0, 0);
            }
    }

    // epilogue: C/D map col=lane&15, row=(lane>>4)*4+q
    #pragma unroll
    for (int j = 0; j < WJ; ++j) {
        const int col = col0 + (wc * WJ + j) * 16 + lrow;
        const float bb = bias[col];
        #pragma unroll
        for (int i = 0; i < 4; ++i) {
            const int rbase = row0 + (wr * 4 + i) * 16 + (l >> 4) * 4;
            #pragma unroll
            for (int q = 0; q < 4; ++q)
                C[(size_t)(rbase + q) * DDIM + col] =
                    acc1[i][j][q] + acc2[i][j][q] * 0.00390625f + bb;
        }
    }
}

// ---------------- feature map: softmax-normalized positive features over hd=64 ----------------
__global__ __launch_bounds__(256) void feature_kernel(float* __restrict__ buf,
                                                      float* __restrict__ den)
{
    const int wid  = blockIdx.x * 4 + (threadIdx.x >> 6);
    const int lane = threadIdx.x & 63;
    const int row = wid >> 4;
    const int h   = wid & 15;
    float* p = buf + (size_t)row * DDIM + h * HD;

    const float v = p[lane];
    float m = v;
    #pragma unroll
    for (int o = 32; o; o >>= 1) m = fmaxf(m, __shfl_xor(m, o, 64));
    const float e = expf(v - m);
    float s = e;
    #pragma unroll
    for (int o = 32; o; o >>= 1) s += __shfl_xor(s, o, 64);
    const float q = e / (s + EPSV);
    p[lane] = q;
    if (den != nullptr) {
        float d = q;
        #pragma unroll
        for (int o = 32; o; o >>= 1) d += __shfl_xor(d, o, 64);
        if (lane == 0) den[wid] = d;
    }
}

// ---------------- KV = Kf^T V per head, 8-way m-split ----------------
#define MSUB 32
__global__ __launch_bounds__(256) void kv_partial_kernel(
    const float* __restrict__ Kf, const float* __restrict__ V, float* __restrict__ KVp)
{
    const int z = blockIdx.x;
    const int chunk = z & 7;
    const int bh = z >> 3;
    const int h = bh & 15;
    const int b = bh >> 4;

    __shared__ float Ks[MSUB][HD];
    __shared__ float Vs[MSUB][HD];

    const int t = threadIdx.x;
    const int d0 = (t >> 4) * 4;
    const int e0 = (t & 15) * 4;
    float acc[4][4];
    #pragma unroll
    for (int i = 0; i < 4; ++i)
        #pragma unroll
        for (int j = 0; j < 4; ++j) acc[i][j] = 0.f;

    const int base_tok = b * 2048 + chunk * 256;
    for (int sc = 0; sc < 8; ++sc) {
        __syncthreads();
        #pragma unroll
        for (int u = 0; u < 2; ++u) {
            const int f = t + u * 256;
            const int tok = f >> 4;
            const int c4 = (f & 15) * 4;
            const size_t g = (size_t)(base_tok + sc * MSUB + tok) * DDIM + h * HD + c4;
            *(float4*)&Ks[tok][c4] = *(const float4*)&Kf[g];
            *(float4*)&Vs[tok][c4] = *(const float4*)&V[g];
        }
        __syncthreads();
        #pragma unroll
        for (int mm = 0; mm < MSUB; ++mm) {
            const float4 k4 = *(const float4*)&Ks[mm][d0];
            const float4 v4 = *(const float4*)&Vs[mm][e0];
            const float kr[4] = {k4.x, k4.y, k4.z, k4.w};
            const float vr[4] = {v4.x, v4.y, v4.z, v4.w};
            #pragma unroll
            for (int i = 0; i < 4; ++i)
                #pragma unroll
                for (int j = 0; j < 4; ++j)
                    acc[i][j] = fmaf(kr[i], vr[j], acc[i][j]);
        }
    }
    float* outp = KVp + (size_t)z * 4096;
    #pragma unroll
    for (int i = 0; i < 4; ++i)
        *(float4*)&outp[(d0 + i) * HD + e0] =
            make_float4(acc[i][0], acc[i][1], acc[i][2], acc[i][3]);
}

__global__ __launch_bounds__(256) void kv_reduce_kernel(const float* __restrict__ KVp,
                                                        float* __restrict__ KV)
{
    const int idx = blockIdx.x * 256 + threadIdx.x;
    const int bh = idx >> 12;
    const int off = idx & 4095;
    float s = 0.f;
    #pragma unroll
    for (int c = 0; c < 8; ++c) s += KVp[(size_t)(bh * 8 + c) * 4096 + off];
    KV[idx] = s;
}

// ---------------- context = qf @ KV / (den+eps) -> fp16 ----------------
__global__ __launch_bounds__(256) void context_kernel(
    const float* __restrict__ QF, const float* __restrict__ KV, const float* __restrict__ den,
    _Float16* __restrict__ Ch)
{
    const int z = blockIdx.x;
    const int tc = z & 31;
    const int bh = z >> 5;
    const int h = bh & 15;
    const int b = bh >> 4;

    __shared__ float KVs[HD][HD];
    const int t = threadIdx.x;
    #pragma unroll
    for (int u = 0; u < 4; ++u) {
        const int f = t + u * 256;
        *(float4*)&KVs[0][f * 4] = *(const float4*)&KV[(size_t)bh * 4096 + f * 4];
    }
    __syncthreads();

    const int wave = t >> 6;
    const int lane = t & 63;
    for (int it = 0; it < 16; ++it) {
        const int tok = tc * 64 + it * 4 + wave;
        const int row = b * 2048 + tok;
        const size_t idx = (size_t)row * DDIM + h * HD + lane;
        const float qv = QF[idx];
        float acc = 0.f;
        #pragma unroll
        for (int e = 0; e < 64; ++e) {
            const float qe = __shfl(qv, e, 64);
            acc = fmaf(qe, KVs[e][lane], acc);
        }
        const float r = acc / (den[row * HEADS + h] + EPSV);
        Ch[idx] = (_Float16)r;
    }
}

// ---------------- launch ----------------
extern "C" void kernel_launch(void* const* d_in, const int* in_sizes, int n_in,
                              void* d_out, int out_size, void* d_ws, size_t ws_size,
                              hipStream_t stream)
{
    const float* X  = (const float*)d_in[0];
    const float* Wq = (const float*)d_in[1];
    const float* bq = (const float*)d_in[2];
    const float* Wk = (const float*)d_in[3];
    const float* bk = (const float*)d_in[4];
    const float* Wv = (const float*)d_in[5];
    const float* bv = (const float*)d_in[6];
    const float* Wo = (const float*)d_in[7];
    const float* bo = (const float*)d_in[8];
    float* out = (float*)d_out;

    // ws (floats): Q|K|V fp32 (48MB) | den | KV | KVp | halfs: Xh (8MB, reused
    // as ctx fp16) | 4x WT hi/lo fp16 (16MB). total ~80MB.
    float* ws  = (float*)d_ws;
    float* Q   = ws;
    float* Kb  = ws + 4194304;
    float* Vb  = ws + 8388608;
    float* den = ws + 12582912;
    float* KV  = den + 65536;
    float* KVp = KV + 131072;
    _Float16* Xh  = (_Float16*)(KVp + 1048576);
    _Float16* Wqh = Xh + 4194304;
    _Float16* Wql = Wqh + 1048576;
    _Float16* Wkh = Wql + 1048576;
    _Float16* Wkl = Wkh + 1048576;
    _Float16* Wvh = Wkl + 1048576;
    _Float16* Wvl = Wvh + 1048576;
    _Float16* Woh = Wvl + 1048576;
    _Float16* Wol = Woh + 1048576;
    _Float16* Ch  = Xh;   // ctx aliases Xh (dead after QKV GEMM)

    // 1) conversions
    xhalf_kernel<<<2048, 256, 0, stream>>>(X, Xh);
    wsplit_kernel<<<dim3(32, 32, 4), 256, 0, stream>>>(
        Wq, Wk, Wv, Wo, Wqh, Wql, Wkh, Wkl, Wvh, Wvl, Woh, Wol);

    // 2) fused QKV projection (fp16 2-product MFMA), 768 blocks
    gemm_mfma<4><<<dim3(32, 8, 3), 256, 0, stream>>>(
        Xh, Wqh, Wql, Wkh, Wkl, Wvh, Wvl, bq, bk, bv, Q, Kb, Vb);

    // 3) positive feature maps (q also stores den)
    feature_kernel<<<16384, 256, 0, stream>>>(Q, den);
    feature_kernel<<<16384, 256, 0, stream>>>(Kb, nullptr);

    // 4) KV = Kf^T V per head
    kv_partial_kernel<<<256, 256, 0, stream>>>(Kb, Vb, KVp);
    kv_reduce_kernel<<<512, 256, 0, stream>>>(KVp, KV);

    // 5) context -> fp16
    context_kernel<<<1024, 256, 0, stream>>>(Q, KV, den, Ch);

    // 6) output projection, BN=64 -> 512 blocks (2 blocks/CU)
    gemm_mfma<2><<<dim3(32, 16, 1), 256, 0, stream>>>(
        Ch, Woh, Wol, Woh, Wol, Woh, Wol, bo, bo, bo, out, out, out);
}

// Round 9
// 304.154 us; speedup vs baseline: 1.1503x; 1.0268x over previous
//
#include <hip/hip_runtime.h>

// PerformerSelfAttention B=2 L=2048 D=1024 H=16 hd=64 fp32.
// Linear-attention identity: ctx = qf @ (Kf^T V) / (sum_d qf + eps).
// GEMMs: fp16 MFMA, B-side hi/lo split (2 products):
//   C = A_f16 * Bh + (A_f16 * Bl_scaled) * 2^-8,  Bl_scaled = (B - Bh)*256
// R8 change: 2-phase double-buffered K-loop (T3-minimum). Stage tile t+1
// into buf^1 BEFORE computing tile t from buf; ONE __syncthreads per step
// (implicit vmcnt(0)+lgkmcnt(0) drain). Hides L2 load latency under
// ds_read+MFMA; halves barrier count. R8 counters showed latency-bound:
// MfmaUtil 20%, VALUBusy 10%, HBM 14%, conflicts 0 -> both pipes idle.

#define EPSV 1e-6f
#define MDIM 4096
#define DDIM 1024
#define HEADS 16
#define HD 64

typedef __attribute__((ext_vector_type(8))) _Float16 half8;
typedef __attribute__((ext_vector_type(4))) _Float16 half4;
typedef __attribute__((ext_vector_type(4))) float f32x4;

__device__ inline void gld_lds16(const _Float16* g, _Float16* l) {
    __builtin_amdgcn_global_load_lds(
        (const __attribute__((address_space(1))) unsigned int*)g,
        (__attribute__((address_space(3))) unsigned int*)l, 16, 0, 0);
}

// ---------------- X fp32 -> fp16 ----------------
__global__ __launch_bounds__(256) void xhalf_kernel(const float* __restrict__ x,
                                                    _Float16* __restrict__ xh)
{
    const int i = (blockIdx.x * 256 + threadIdx.x) * 8;
    const float4 v0 = *(const float4*)&x[i];
    const float4 v1 = *(const float4*)&x[i + 4];
    half8 h;
    h[0] = (_Float16)v0.x; h[1] = (_Float16)v0.y; h[2] = (_Float16)v0.z; h[3] = (_Float16)v0.w;
    h[4] = (_Float16)v1.x; h[5] = (_Float16)v1.y; h[6] = (_Float16)v1.z; h[7] = (_Float16)v1.w;
    *(half8*)&xh[i] = h;
}

// ---------------- W[k][n] fp32 -> WT hi [n][k] fp16, WT lo-scaled [n][k] fp16 ----------------
__global__ __launch_bounds__(256) void wsplit_kernel(
    const float* __restrict__ W0, const float* __restrict__ W1,
    const float* __restrict__ W2, const float* __restrict__ W3,
    _Float16* __restrict__ T0h, _Float16* __restrict__ T0l,
    _Float16* __restrict__ T1h, _Float16* __restrict__ T1l,
    _Float16* __restrict__ T2h, _Float16* __restrict__ T2l,
    _Float16* __restrict__ T3h, _Float16* __restrict__ T3l)
{
    const float* W; _Float16* Th; _Float16* Tl;
    if (blockIdx.z == 0)      { W = W0; Th = T0h; Tl = T0l; }
    else if (blockIdx.z == 1) { W = W1; Th = T1h; Tl = T1l; }
    else if (blockIdx.z == 2) { W = W2; Th = T2h; Tl = T2l; }
    else                      { W = W3; Th = T3h; Tl = T3l; }

    __shared__ float t[32][33];
    const int tt = threadIdx.x;
    const int r = tt >> 3, c4 = (tt & 7) * 4;
    const int k0 = blockIdx.x * 32, n0 = blockIdx.y * 32;

    const float4 v = *(const float4*)&W[(size_t)(k0 + r) * DDIM + n0 + c4];
    t[r][c4 + 0] = v.x; t[r][c4 + 1] = v.y; t[r][c4 + 2] = v.z; t[r][c4 + 3] = v.w;
    __syncthreads();

    const float x0 = t[c4 + 0][r], x1 = t[c4 + 1][r], x2 = t[c4 + 2][r], x3 = t[c4 + 3][r];
    half4 h, l;
    h[0] = (_Float16)x0; l[0] = (_Float16)((x0 - (float)h[0]) * 256.0f);
    h[1] = (_Float16)x1; l[1] = (_Float16)((x1 - (float)h[1]) * 256.0f);
    h[2] = (_Float16)x2; l[2] = (_Float16)((x2 - (float)h[2]) * 256.0f);
    h[3] = (_Float16)x3; l[3] = (_Float16)((x3 - (float)h[3]) * 256.0f);
    *(half4*)&Th[(size_t)(n0 + r) * DDIM + k0 + c4] = h;
    *(half4*)&Tl[(size_t)(n0 + r) * DDIM + k0 + c4] = l;
}

// ---------------- fp16 2-product MFMA GEMM, 2-phase pipelined ----------------
// Block tile 128 x (32*WJ), BK=32, 4 waves (2x2), wave tile 64 x (16*WJ).
// LDS fragment-major, double-buffered: 2 x NF frags x 1KB.
template<int WJ>
__global__ __launch_bounds__(256, 2) void gemm_mfma(
    const _Float16* __restrict__ A,
    const _Float16* __restrict__ B0h, const _Float16* __restrict__ B0l,
    const _Float16* __restrict__ B1h, const _Float16* __restrict__ B1l,
    const _Float16* __restrict__ B2h, const _Float16* __restrict__ B2l,
    const float* __restrict__ bias0, const float* __restrict__ bias1, const float* __restrict__ bias2,
    float* __restrict__ C0, float* __restrict__ C1, float* __restrict__ C2)
{
    const _Float16* Bh; const _Float16* Bl; const float* bias; float* C;
    if (blockIdx.z == 0)      { Bh = B0h; Bl = B0l; bias = bias0; C = C0; }
    else if (blockIdx.z == 1) { Bh = B1h; Bl = B1l; bias = bias1; C = C1; }
    else                      { Bh = B2h; Bl = B2l; bias = bias2; C = C2; }

    constexpr int FA = 8;           // A frags (128 rows)
    constexpr int FB = 2 * WJ;      // Bh frags (= Bl frags)
    constexpr int NF = FA + 2 * FB;
    constexpr int FPW = NF / 4;     // frags staged per wave
    constexpr int NT = DDIM / 32;   // 32 K-steps

    __shared__ __align__(16) _Float16 lds[2][NF * 512];

    const int tid = threadIdx.x;
    const int w = tid >> 6, l = tid & 63;
    const int row0 = blockIdx.x * 128, col0 = blockIdx.y * (32 * WJ);
    const int wr = w >> 1, wc = w & 1;

    const int lrow = (l & 15);
    const int lk   = (l >> 4) * 8;

    // per-wave staging sources (wave-uniform), precomputed
    const _Float16* gsrc[FPW];
    #pragma unroll
    for (int u = 0; u < FPW; ++u) {
        const int g = w * FPW + u;
        const _Float16* src; int outer;
        if (g < FA)           { src = A;  outer = row0 + g * 16; }
        else if (g < FA + FB) { src = Bh; outer = col0 + (g - FA) * 16; }
        else                  { src = Bl; outer = col0 + (g - FA - FB) * 16; }
        gsrc[u] = src + (size_t)(outer + lrow) * DDIM + lk;
    }

    f32x4 acc1[4][WJ], acc2[4][WJ];
    #pragma unroll
    for (int i = 0; i < 4; ++i)
        #pragma unroll
        for (int j = 0; j < WJ; ++j) {
            acc1[i][j] = (f32x4){0.f, 0.f, 0.f, 0.f};
            acc2[i][j] = (f32x4){0.f, 0.f, 0.f, 0.f};
        }

    // prologue: stage tile 0 into buf 0; barrier drains vmcnt(0)
    #pragma unroll
    for (int u = 0; u < FPW; ++u)
        gld_lds16(gsrc[u], &lds[0][(w * FPW + u) * 512]);
    __syncthreads();

    int cur = 0;
    for (int t = 0; t < NT; ++t) {
        // issue next tile's staging into the other buffer (hidden under compute)
        if (t + 1 < NT) {
            const int kc = (t + 1) * 32;
            #pragma unroll
            for (int u = 0; u < FPW; ++u)
                gld_lds16(gsrc[u] + kc, &lds[cur ^ 1][(w * FPW + u) * 512]);
        }

        const _Float16* lbase = &lds[cur][0];
        half8 a[4], bh[WJ], bl[WJ];
        #pragma unroll
        for (int i = 0; i < 4; ++i)
            a[i] = *(const half8*)&lbase[(wr * 4 + i) * 512 + l * 8];
        #pragma unroll
        for (int j = 0; j < WJ; ++j) {
            bh[j] = *(const half8*)&lbase[(FA + wc * WJ + j) * 512 + l * 8];
            bl[j] = *(const half8*)&lbase[(FA + FB + wc * WJ + j) * 512 + l * 8];
        }
        #pragma unroll
        for (int i = 0; i < 4; ++i)
            #pragma unroll
            for (int j = 0; j < WJ; ++j) {
                acc1[i][j] = __builtin_amdgcn_mfma_f32_16x16x32_f16(a[i], bh[j], acc1[i][j], 0, 0, 0);
                acc2[i][j] = __builtin_amdgcn_mfma_f32_16x16x32_f16(a[i], bl[j], acc2[i][j], 0, 0, 0);
            }

        // one barrier per K-step: drains vmcnt(0) (next tile staged) and
        // orders this tile's reads (done: MFMAs consumed them) before reuse.
        __syncthreads();
        cur ^= 1;
    }

    // epilogue: C/D map col=lane&15, row=(lane>>4)*4+q
    #pragma unroll
    for (int j = 0; j < WJ; ++j) {
        const int col = col0 + (wc * WJ + j) * 16 + lrow;
        const float bb = bias[col];
        #pragma unroll
        for (int i = 0; i < 4; ++i) {
            const int rbase = row0 + (wr * 4 + i) * 16 + (l >> 4) * 4;
            #pragma unroll
            for (int q = 0; q < 4; ++q)
                C[(size_t)(rbase + q) * DDIM + col] =
                    acc1[i][j][q] + acc2[i][j][q] * 0.00390625f + bb;
        }
    }
}

// ---------------- feature map: softmax-normalized positive features over hd=64 ----------------
__global__ __launch_bounds__(256) void feature_kernel(float* __restrict__ buf,
                                                      float* __restrict__ den)
{
    const int wid  = blockIdx.x * 4 + (threadIdx.x >> 6);
    const int lane = threadIdx.x & 63;
    const int row = wid >> 4;
    const int h   = wid & 15;
    float* p = buf + (size_t)row * DDIM + h * HD;

    const float v = p[lane];
    float m = v;
    #pragma unroll
    for (int o = 32; o; o >>= 1) m = fmaxf(m, __shfl_xor(m, o, 64));
    const float e = expf(v - m);
    float s = e;
    #pragma unroll
    for (int o = 32; o; o >>= 1) s += __shfl_xor(s, o, 64);
    const float q = e / (s + EPSV);
    p[lane] = q;
    if (den != nullptr) {
        float d = q;
        #pragma unroll
        for (int o = 32; o; o >>= 1) d += __shfl_xor(d, o, 64);
        if (lane == 0) den[wid] = d;
    }
}

// ---------------- KV = Kf^T V per head, 8-way m-split ----------------
#define MSUB 32
__global__ __launch_bounds__(256) void kv_partial_kernel(
    const float* __restrict__ Kf, const float* __restrict__ V, float* __restrict__ KVp)
{
    const int z = blockIdx.x;
    const int chunk = z & 7;
    const int bh = z >> 3;
    const int h = bh & 15;
    const int b = bh >> 4;

    __shared__ float Ks[MSUB][HD];
    __shared__ float Vs[MSUB][HD];

    const int t = threadIdx.x;
    const int d0 = (t >> 4) * 4;
    const int e0 = (t & 15) * 4;
    float acc[4][4];
    #pragma unroll
    for (int i = 0; i < 4; ++i)
        #pragma unroll
        for (int j = 0; j < 4; ++j) acc[i][j] = 0.f;

    const int base_tok = b * 2048 + chunk * 256;
    for (int sc = 0; sc < 8; ++sc) {
        __syncthreads();
        #pragma unroll
        for (int u = 0; u < 2; ++u) {
            const int f = t + u * 256;
            const int tok = f >> 4;
            const int c4 = (f & 15) * 4;
            const size_t g = (size_t)(base_tok + sc * MSUB + tok) * DDIM + h * HD + c4;
            *(float4*)&Ks[tok][c4] = *(const float4*)&Kf[g];
            *(float4*)&Vs[tok][c4] = *(const float4*)&V[g];
        }
        __syncthreads();
        #pragma unroll
        for (int mm = 0; mm < MSUB; ++mm) {
            const float4 k4 = *(const float4*)&Ks[mm][d0];
            const float4 v4 = *(const float4*)&Vs[mm][e0];
            const float kr[4] = {k4.x, k4.y, k4.z, k4.w};
            const float vr[4] = {v4.x, v4.y, v4.z, v4.w};
            #pragma unroll
            for (int i = 0; i < 4; ++i)
                #pragma unroll
                for (int j = 0; j < 4; ++j)
                    acc[i][j] = fmaf(kr[i], vr[j], acc[i][j]);
        }
    }
    float* outp = KVp + (size_t)z * 4096;
    #pragma unroll
    for (int i = 0; i < 4; ++i)
        *(float4*)&outp[(d0 + i) * HD + e0] =
            make_float4(acc[i][0], acc[i][1], acc[i][2], acc[i][3]);
}

__global__ __launch_bounds__(256) void kv_reduce_kernel(const float* __restrict__ KVp,
                                                        float* __restrict__ KV)
{
    const int idx = blockIdx.x * 256 + threadIdx.x;
    const int bh = idx >> 12;
    const int off = idx & 4095;
    float s = 0.f;
    #pragma unroll
    for (int c = 0; c < 8; ++c) s += KVp[(size_t)(bh * 8 + c) * 4096 + off];
    KV[idx] = s;
}

// ---------------- context = qf @ KV / (den+eps) -> fp16 ----------------
__global__ __launch_bounds__(256) void context_kernel(
    const float* __restrict__ QF, const float* __restrict__ KV, const float* __restrict__ den,
    _Float16* __restrict__ Ch)
{
    const int z = blockIdx.x;
    const int tc = z & 31;
    const int bh = z >> 5;
    const int h = bh & 15;
    const int b = bh >> 4;

    __shared__ float KVs[HD][HD];
    const int t = threadIdx.x;
    #pragma unroll
    for (int u = 0; u < 4; ++u) {
        const int f = t + u * 256;
        *(float4*)&KVs[0][f * 4] = *(const float4*)&KV[(size_t)bh * 4096 + f * 4];
    }
    __syncthreads();

    const int wave = t >> 6;
    const int lane = t & 63;
    for (int it = 0; it < 16; ++it) {
        const int tok = tc * 64 + it * 4 + wave;
        const int row = b * 2048 + tok;
        const size_t idx = (size_t)row * DDIM + h * HD + lane;
        const float qv = QF[idx];
        float acc = 0.f;
        #pragma unroll
        for (int e = 0; e < 64; ++e) {
            const float qe = __shfl(qv, e, 64);
            acc = fmaf(qe, KVs[e][lane], acc);
        }
        const float r = acc / (den[row * HEADS + h] + EPSV);
        Ch[idx] = (_Float16)r;
    }
}

// ---------------- launch ----------------
extern "C" void kernel_launch(void* const* d_in, const int* in_sizes, int n_in,
                              void* d_out, int out_size, void* d_ws, size_t ws_size,
                              hipStream_t stream)
{
    const float* X  = (const float*)d_in[0];
    const float* Wq = (const float*)d_in[1];
    const float* bq = (const float*)d_in[2];
    const float* Wk = (const float*)d_in[3];
    const float* bk = (const float*)d_in[4];
    const float* Wv = (const float*)d_in[5];
    const float* bv = (const float*)d_in[6];
    const float* Wo = (const float*)d_in[7];
    const float* bo = (const float*)d_in[8];
    float* out = (float*)d_out;

    // ws (floats): Q|K|V fp32 (48MB) | den | KV | KVp | halfs: Xh (8MB, reused
    // as ctx fp16) | 4x WT hi/lo fp16 (16MB). total ~80MB.
    float* ws  = (float*)d_ws;
    float* Q   = ws;
    float* Kb  = ws + 4194304;
    float* Vb  = ws + 8388608;
    float* den = ws + 12582912;
    float* KV  = den + 65536;
    float* KVp = KV + 131072;
    _Float16* Xh  = (_Float16*)(KVp + 1048576);
    _Float16* Wqh = Xh + 4194304;
    _Float16* Wql = Wqh + 1048576;
    _Float16* Wkh = Wql + 1048576;
    _Float16* Wkl = Wkh + 1048576;
    _Float16* Wvh = Wkl + 1048576;
    _Float16* Wvl = Wvh + 1048576;
    _Float16* Woh = Wvl + 1048576;
    _Float16* Wol = Woh + 1048576;
    _Float16* Ch  = Xh;   // ctx aliases Xh (dead after QKV GEMM)

    // 1) conversions
    xhalf_kernel<<<2048, 256, 0, stream>>>(X, Xh);
    wsplit_kernel<<<dim3(32, 32, 4), 256, 0, stream>>>(
        Wq, Wk, Wv, Wo, Wqh, Wql, Wkh, Wkl, Wvh, Wvl, Woh, Wol);

    // 2) fused QKV projection (fp16 2-product MFMA, 2-phase), 768 blocks
    gemm_mfma<4><<<dim3(32, 8, 3), 256, 0, stream>>>(
        Xh, Wqh, Wql, Wkh, Wkl, Wvh, Wvl, bq, bk, bv, Q, Kb, Vb);

    // 3) positive feature maps (q also stores den)
    feature_kernel<<<16384, 256, 0, stream>>>(Q, den);
    feature_kernel<<<16384, 256, 0, stream>>>(Kb, nullptr);

    // 4) KV = Kf^T V per head
    kv_partial_kernel<<<256, 256, 0, stream>>>(Kb, Vb, KVp);
    kv_reduce_kernel<<<512, 256, 0, stream>>>(KVp, KV);

    // 5) context -> fp16
    context_kernel<<<1024, 256, 0, stream>>>(Q, KV, den, Ch);

    // 6) output projection, BN=64 -> 512 blocks (2 blocks/CU)
    gemm_mfma<2><<<dim3(32, 16, 1), 256, 0, stream>>>(
        Ch, Woh, Wol, Woh, Wol, Woh, Wol, bo, bo, bo, out, out, out);
}